// Round 9
// baseline (529.378 us; speedup 1.0000x reference)
//
#include <hip/hip_runtime.h>
#include <hip/hip_bf16.h>
#include <cstdint>
#include <cstddef>

#define NN 100000      // nodes
#define NE 1600000     // edges
#define HH 128         // hidden dim
#define NG 256         // graphs

#define NB 196         // buckets (512 nodes each; 196*512 = 100352 >= NN)
#define BSH 9          // bucket shift
#define BMSK 511
#define CHUNK 4096     // edges per binning block
#define CSH 12         // log2(CHUNK)
#define NBLK 391       // ceil(NE / CHUNK)
#define GB 782         // GEMM blocks: ceil(NN/128)
#define NBK 391        // ceil(NN/256)
#define NBZ 300        // ceil(NB*NBLK / 256) -- blkcntB zero-init blocks

typedef __bf16 bf16x8 __attribute__((ext_vector_type(8)));
typedef float floatx4 __attribute__((ext_vector_type(4)));

__device__ __forceinline__ uint32_t f2b(float f) {
  union { float f; uint32_t u; } v; v.f = f;
  uint32_t u = v.u;
  return (u + 0x7FFFu + ((u >> 16) & 1u)) >> 16;   // RNE to bf16 (raw 16 bits)
}
// bf16 lane unpack: low half = u<<16, high half = u & 0xFFFF0000 (1 VALU op each)
__device__ __forceinline__ float blo(uint32_t u) {
  union { uint32_t u; float f; } v; v.u = u << 16;
  return v.f;
}
__device__ __forceinline__ float bhi(uint32_t u) {
  union { uint32_t u; float f; } v; v.u = u & 0xFFFF0000u;
  return v.f;
}
__device__ __forceinline__ void addrow(float* a, uint4 v) {
  a[0] += blo(v.x); a[1] += bhi(v.x);
  a[2] += blo(v.y); a[3] += bhi(v.y);
  a[4] += blo(v.z); a[5] += bhi(v.z);
  a[6] += blo(v.w); a[7] += bhi(v.w);
}

__device__ __forceinline__ void stage_w(uint16_t (*Wt)[136], const float* __restrict__ W,
                                        int tid) {
  for (int it = 0; it < 16; ++it) {
    int idx = tid + it * 256;
    int n = idx & 127;
    int k0 = (idx >> 7) * 4;
    uint2 wv;
    wv.x = f2b(W[(k0 + 0) * 128 + n]) | (f2b(W[(k0 + 1) * 128 + n]) << 16);
    wv.y = f2b(W[(k0 + 2) * 128 + n]) | (f2b(W[(k0 + 3) * 128 + n]) << 16);
    *(uint2*)&Wt[n][k0] = wv;
  }
}

// ================= L1: cntA || wprep || pooled zero || blkcntB zero =================
// blkcnt layouts are TRANSPOSED: blkcnt[t*NBLK + r] (column-major) so the scan
// kernel reads each bucket's chunk-counts contiguously.
__global__ __launch_bounds__(256) void k_front(const int* __restrict__ src,
                                               int* __restrict__ blkcntA,
                                               int* __restrict__ blkcntB,
                                               const float* __restrict__ conv_w,
                                               uint16_t* __restrict__ wbf,
                                               float* __restrict__ pooled) {
  int t = threadIdx.x;
  if (blockIdx.x < NBLK) {
    __shared__ int h[NB];
    if (t < NB) h[t] = 0;
    __syncthreads();
    int base = blockIdx.x * CHUNK, end = min(base + CHUNK, NE);
    for (int i = base + t; i < end; i += 256) atomicAdd(&h[src[i] >> BSH], 1);
    __syncthreads();
    if (t < NB) blkcntA[t * NBLK + blockIdx.x] = h[t];
  } else if (blockIdx.x < NBLK + 128) {
    // conv layers 1,2 fp32 [k][n] -> bf16 [n][k]; same f2b rounding as stage_w
    int idx = (blockIdx.x - NBLK) * 256 + t;   // 0..32767
    int l = idx >> 14;
    int n = (idx >> 7) & 127;
    int k = idx & 127;
    wbf[idx] = (uint16_t)f2b(conv_w[(l + 1) * 16384 + k * 128 + n]);
  } else if (blockIdx.x < NBLK + 128 + 32) {
    int i = ((blockIdx.x - NBLK - 128) * 256 + t) * 4;   // 32 blocks x 1024 floats
    if (i < NG * HH) *(float4*)&pooled[i] = make_float4(0.f, 0.f, 0.f, 0.f);
  } else {
    int i = (blockIdx.x - NBLK - 160) * 256 + t;         // NBZ=300 blocks: zero blkcntB
    if (i < NB * NBLK) blkcntB[i] = 0;                   // 76,636 ints (r8 bug: only 75 blocks)
  }
}

// merged column-scan + global-scan over TRANSPOSED blkcnt: 1 block.
// 8-wide blocked loads so the accumulation pipelines.
__global__ void k_scan(const int* __restrict__ blkcnt, int* __restrict__ poff,
                       int* __restrict__ gbase, int* __restrict__ off, int set_off) {
  __shared__ int s[256];
  int t = threadIdx.x;
  int tot = 0;
  if (t < NB) {
    const int* col = blkcnt + (size_t)t * NBLK;
    int* pcol = poff + (size_t)t * NBLK;
    int r0 = 0;
    for (; r0 + 8 <= NBLK; r0 += 8) {
      int v[8];
#pragma unroll
      for (int j = 0; j < 8; ++j) v[j] = col[r0 + j];
#pragma unroll
      for (int j = 0; j < 8; ++j) { pcol[r0 + j] = tot; tot += v[j]; }
    }
    for (; r0 < NBLK; ++r0) { pcol[r0] = tot; tot += col[r0]; }
  }
  s[t] = (t < NB) ? tot : 0;
  __syncthreads();
  for (int d = 1; d < 256; d <<= 1) {
    int v = (t >= d) ? s[t - d] : 0;
    __syncthreads();
    s[t] += v;
    __syncthreads();
  }
  if (t < NB) gbase[t] = s[t] - tot;
  if (t == 0) { gbase[NB] = NE; if (set_off) off[NN] = NE; }
}

// ================= L3: placeA (src-bucket sort) + fused cntB =================
// For the pair placed at position p, count bucket(dst) in output-chunk p>>CSH —
// identical to the old cntB pass over pairsA, without re-reading 12.8 MB.
__global__ __launch_bounds__(256) void k_placeA(const int* __restrict__ src,
                                                const int* __restrict__ dst,
                                                const int* __restrict__ poff,
                                                const int* __restrict__ gbase,
                                                uint2* __restrict__ pairs,
                                                int* __restrict__ blkcntB) {
  __shared__ int cur[NB];
  int t = threadIdx.x;
  if (t < NB) cur[t] = poff[(size_t)t * NBLK + blockIdx.x] + gbase[t];
  __syncthreads();
  int base = blockIdx.x * CHUNK, end = min(base + CHUNK, NE);
  for (int i = base + t; i < end; i += 256) {
    int s = src[i], d = dst[i];
    int p = atomicAdd(&cur[s >> BSH], 1);
    pairs[p] = make_uint2((unsigned)s, (unsigned)d);
    atomicAdd(&blkcntB[(d >> BSH) * NBLK + (p >> CSH)], 1);
  }
}

__global__ __launch_bounds__(256) void k_placeB(const uint2* __restrict__ pairs,
                                                const int* __restrict__ poff,
                                                const int* __restrict__ gbase,
                                                uint32_t* __restrict__ outb) {
  __shared__ int cur[NB];
  int t = threadIdx.x;
  if (t < NB) cur[t] = poff[(size_t)t * NBLK + blockIdx.x] + gbase[t];
  __syncthreads();
  int base = blockIdx.x * CHUNK, end = min(base + CHUNK, NE);
  for (int i = base + t; i < end; i += 256) {
    uint2 v = pairs[i];
    int p = atomicAdd(&cur[v.y >> BSH], 1);
    outb[p] = v.x | ((v.y & (unsigned)BMSK) << 17);
  }
}

// ================= L6: bucket_sort || enc1 GEMM =================
__global__ __launch_bounds__(256) void k_sortenc(
    const uint32_t* __restrict__ pairbuf, const int* __restrict__ gbase,
    const int* __restrict__ batch,
    int* __restrict__ off, int* __restrict__ csrs,
    int* __restrict__ dhist2, int* __restrict__ gstart,
    const float* __restrict__ A32, const float* __restrict__ W,
    const float* __restrict__ bias, uint16_t* __restrict__ Out)
{
  __shared__ char smraw[34816];
  const int tid = threadIdx.x;

  if (blockIdx.x < GB) {
    // ---------------- enc1 GEMM ----------------
    auto Wt = (uint16_t(*)[136])smraw;
    stage_w(Wt, W, tid);
    __syncthreads();

    const int lane = tid & 63;
    const int wave = tid >> 6;
    const int lrow = lane & 15;
    const int quad = lane >> 4;
    const int lk = quad * 8;
    const int row0 = blockIdx.x * 128 + wave * 32;

    floatx4 acc[2][8];
#pragma unroll
    for (int t = 0; t < 2; ++t)
#pragma unroll
      for (int n = 0; n < 8; ++n)
        acc[t][n] = (floatx4){0.f, 0.f, 0.f, 0.f};

#pragma unroll
    for (int ks = 0; ks < 4; ++ks) {
      bf16x8 a[2];
#pragma unroll
      for (int t = 0; t < 2; ++t) {
        int r = row0 + t * 16 + lrow;
        uint4 tmp = {0u, 0u, 0u, 0u};
        if (r < NN) {
          float4 f0 = *(const float4*)(A32 + (size_t)r * HH + ks * 32 + lk);
          float4 f1 = *(const float4*)(A32 + (size_t)r * HH + ks * 32 + lk + 4);
          tmp.x = f2b(f0.x) | (f2b(f0.y) << 16);
          tmp.y = f2b(f0.z) | (f2b(f0.w) << 16);
          tmp.z = f2b(f1.x) | (f2b(f1.y) << 16);
          tmp.w = f2b(f1.z) | (f2b(f1.w) << 16);
        }
        a[t] = __builtin_bit_cast(bf16x8, tmp);
      }
#pragma unroll
      for (int n = 0; n < 8; ++n) {
        bf16x8 b = __builtin_bit_cast(bf16x8, *(const uint4*)&Wt[n * 16 + lrow][ks * 32 + lk]);
        acc[0][n] = __builtin_amdgcn_mfma_f32_16x16x32_bf16(b, a[0], acc[0][n], 0, 0, 0);
        acc[1][n] = __builtin_amdgcn_mfma_f32_16x16x32_bf16(b, a[1], acc[1][n], 0, 0, 0);
      }
    }

    float4 b4[8];
#pragma unroll
    for (int n = 0; n < 8; ++n) b4[n] = *(const float4*)(bias + n * 16 + quad * 4);

#pragma unroll
    for (int t = 0; t < 2; ++t) {
      int row = row0 + t * 16 + lrow;
      if (row < NN) {
        uint16_t* orow = Out + (size_t)row * HH;
#pragma unroll
        for (int n = 0; n < 8; ++n) {
          float v0 = fmaxf(acc[t][n][0] + b4[n].x, 0.f);
          float v1 = fmaxf(acc[t][n][1] + b4[n].y, 0.f);
          float v2 = fmaxf(acc[t][n][2] + b4[n].z, 0.f);
          float v3 = fmaxf(acc[t][n][3] + b4[n].w, 0.f);
          uint2 o;
          o.x = f2b(v0) | (f2b(v1) << 16);
          o.y = f2b(v2) | (f2b(v3) << 16);
          *(uint2*)(orow + n * 16 + quad * 4) = o;
        }
      }
    }
  } else {
    // ---------------- bucket_sort ----------------
    int* cnt  = (int*)smraw;        // 512
    int* loff = cnt + 512;          // 512
    int* psum = loff + 512;         // 256
    int b = blockIdx.x - GB;
    cnt[tid] = 0; cnt[tid + 256] = 0;
    __syncthreads();
    int s0 = gbase[b], s1 = gbase[b + 1];
    for (int i = s0 + tid; i < s1; i += 256)
      atomicAdd(&cnt[pairbuf[i] >> 17], 1);
    __syncthreads();
    int a0 = cnt[2 * tid], a1 = cnt[2 * tid + 1];
    int s = a0 + a1;
    psum[tid] = s;
    __syncthreads();
    for (int d = 1; d < 256; d <<= 1) {
      int v = (tid >= d) ? psum[tid - d] : 0;
      __syncthreads();
      psum[tid] += v;
      __syncthreads();
    }
    int excl = psum[tid] - s;
    loff[2 * tid] = excl;
    loff[2 * tid + 1] = excl + a0;
    __syncthreads();
    int* h64 = psum;               // psum dead after excl computed
    if (tid < 64) h64[tid] = 0;
    __syncthreads();
#pragma unroll
    for (int k = 0; k < 2; ++k) {
      int i = tid + k * 256;
      int node = b * 512 + i;
      if (node < NN) {
        off[node] = s0 + loff[i];
        int d = cnt[i]; if (d > 63) d = 63;
        atomicAdd(&h64[d], 1);
      }
    }
    // gstart for this block's node range (batch sorted)
    {
      int n0 = b * 512, n1 = min(n0 + 512, NN);
      for (int i = n0 + tid; i < n1; i += 256) {
        int bb = batch[i];
        if (i == 0) { for (int g = 0; g <= bb; ++g) gstart[g] = 0; }
        else { int aa = batch[i - 1]; for (int g = aa + 1; g <= bb; ++g) gstart[g] = i; }
        if (i == NN - 1) { for (int g = bb + 1; g <= NG; ++g) gstart[g] = NN; }
      }
    }
    __syncthreads();
    if (tid < 64) dhist2[b * 64 + tid] = h64[tid];
    cnt[tid] = loff[tid]; cnt[tid + 256] = loff[tid + 256];   // counters -> cursors
    __syncthreads();
    for (int i = s0 + tid; i < s1; i += 256) {
      uint32_t v = pairbuf[i];
      int p = atomicAdd(&cnt[v >> 17], 1);
      csrs[s0 + p] = (int)(v & 0x1FFFFu);
    }
  }
}

// ================= L7: dscan (block 0) || inv from off-diffs =================
__global__ __launch_bounds__(256) void k_dinv(const int* __restrict__ dhist2,
                                              int* __restrict__ dcur,
                                              const int* __restrict__ off,
                                              float* __restrict__ inv) {
  if (blockIdx.x == 0) {
    int t = threadIdx.x;
    if (t < 64) {
      int sum = 0;
      for (int r = 0; r < NB; ++r) sum += dhist2[r * 64 + (63 - t)];
      int v = sum;
      for (int d = 1; d < 64; d <<= 1) { int u = __shfl_up(v, d); if (t >= d) v += u; }
      dcur[63 - t] = v - sum;
    }
  } else {
    int i = (blockIdx.x - 1) * 256 + threadIdx.x;
    if (i < NN) inv[i] = rsqrtf((float)(off[i + 1] - off[i]) + 1.0f);
  }
}

// ================= L8: fused dual GEMM (enc2+conv0, prescale) || dplace =================
__global__ __launch_bounds__(256) void k_dualplace(
    const uint16_t* __restrict__ A16,
    const float* __restrict__ Wa, const float* __restrict__ ba,
    const float* __restrict__ Wb, const float* __restrict__ bb,
    const float* __restrict__ scale, uint16_t* __restrict__ Out,
    const int* __restrict__ off, int* __restrict__ dcur, int* __restrict__ order)
{
  __shared__ uint16_t Wt[128][136];
  __shared__ uint16_t tile[128][136];
  const int tid = threadIdx.x;

  if (blockIdx.x < GB) {
    // ---------------- dual GEMM ----------------
    stage_w(Wt, Wa, tid);
    __syncthreads();

    const int lane = tid & 63;
    const int wave = tid >> 6;
    const int lrow = lane & 15;
    const int quad = lane >> 4;
    const int lk = quad * 8;
    const int row0 = blockIdx.x * 128 + wave * 32;
    const int trow0 = wave * 32;

    floatx4 acc[2][8];
#pragma unroll
    for (int t = 0; t < 2; ++t)
#pragma unroll
      for (int n = 0; n < 8; ++n)
        acc[t][n] = (floatx4){0.f, 0.f, 0.f, 0.f};

    // phase 1: global A -> C1 (swapped layout)
#pragma unroll
    for (int ks = 0; ks < 4; ++ks) {
      bf16x8 a[2];
#pragma unroll
      for (int t = 0; t < 2; ++t) {
        int r = row0 + t * 16 + lrow;
        uint4 tmp = {0u, 0u, 0u, 0u};
        if (r < NN) tmp = *(const uint4*)(A16 + (size_t)r * HH + ks * 32 + lk);
        a[t] = __builtin_bit_cast(bf16x8, tmp);
      }
#pragma unroll
      for (int n = 0; n < 8; ++n) {
        bf16x8 b = __builtin_bit_cast(bf16x8, *(const uint4*)&Wt[n * 16 + lrow][ks * 32 + lk]);
        acc[0][n] = __builtin_amdgcn_mfma_f32_16x16x32_bf16(b, a[0], acc[0][n], 0, 0, 0);
        acc[1][n] = __builtin_amdgcn_mfma_f32_16x16x32_bf16(b, a[1], acc[1][n], 0, 0, 0);
      }
    }

    // epilogue 1 -> LDS tile (bias, no relu)
    {
      float4 b4[8];
#pragma unroll
      for (int n = 0; n < 8; ++n) b4[n] = *(const float4*)(ba + n * 16 + quad * 4);
#pragma unroll
      for (int t = 0; t < 2; ++t) {
        int trow = trow0 + t * 16 + lrow;
#pragma unroll
        for (int n = 0; n < 8; ++n) {
          uint2 o;
          o.x = f2b(acc[t][n][0] + b4[n].x) | (f2b(acc[t][n][1] + b4[n].y) << 16);
          o.y = f2b(acc[t][n][2] + b4[n].z) | (f2b(acc[t][n][3] + b4[n].w) << 16);
          *(uint2*)&tile[trow][n * 16 + quad * 4] = o;
        }
      }
    }
    __syncthreads();
    stage_w(Wt, Wb, tid);
#pragma unroll
    for (int t = 0; t < 2; ++t)
#pragma unroll
      for (int n = 0; n < 8; ++n)
        acc[t][n] = (floatx4){0.f, 0.f, 0.f, 0.f};
    __syncthreads();

    // phase 2: LDS tile A -> C2
#pragma unroll
    for (int ks = 0; ks < 4; ++ks) {
      bf16x8 a[2];
#pragma unroll
      for (int t = 0; t < 2; ++t)
        a[t] = __builtin_bit_cast(bf16x8,
                 *(const uint4*)&tile[trow0 + t * 16 + lrow][ks * 32 + lk]);
#pragma unroll
      for (int n = 0; n < 8; ++n) {
        bf16x8 b = __builtin_bit_cast(bf16x8, *(const uint4*)&Wt[n * 16 + lrow][ks * 32 + lk]);
        acc[0][n] = __builtin_amdgcn_mfma_f32_16x16x32_bf16(b, a[0], acc[0][n], 0, 0, 0);
        acc[1][n] = __builtin_amdgcn_mfma_f32_16x16x32_bf16(b, a[1], acc[1][n], 0, 0, 0);
      }
    }

    // epilogue 2 -> global (bias, scale, no relu)
    {
      float4 b4[8];
#pragma unroll
      for (int n = 0; n < 8; ++n) b4[n] = *(const float4*)(bb + n * 16 + quad * 4);
#pragma unroll
      for (int t = 0; t < 2; ++t) {
        int row = row0 + t * 16 + lrow;
        if (row < NN) {
          float sc = scale[row];
          uint16_t* orow = Out + (size_t)row * HH;
#pragma unroll
          for (int n = 0; n < 8; ++n) {
            float v0 = (acc[t][n][0] + b4[n].x) * sc;
            float v1 = (acc[t][n][1] + b4[n].y) * sc;
            float v2 = (acc[t][n][2] + b4[n].z) * sc;
            float v3 = (acc[t][n][3] + b4[n].w) * sc;
            uint2 o;
            o.x = f2b(v0) | (f2b(v1) << 16);
            o.y = f2b(v2) | (f2b(v3) << 16);
            *(uint2*)(orow + n * 16 + quad * 4) = o;
          }
        }
      }
    }
  } else {
    // ---------------- dplace (degree-LPT order) ----------------
    int* h = (int*)Wt;
    int* base = h + 64;
    if (tid < 64) h[tid] = 0;
    __syncthreads();
    int i = (blockIdx.x - GB) * 256 + tid;
    int d = 0, ld = 0;
    if (i < NN) { d = off[i + 1] - off[i]; if (d > 63) d = 63; ld = atomicAdd(&h[d], 1); }
    __syncthreads();
    if (tid < 64) base[tid] = h[tid] ? atomicAdd(&dcur[tid], h[tid]) : 0;
    __syncthreads();
    if (i < NN) order[base[d] + ld] = i;
  }
}

// ================= fused agg + conv GEMM (v2: W from L1-resident global) =================
// 512 threads = 32 nodes (16 lanes/node). Gather-sum -> XOR-swizzled LDS S-tile ->
// 8 waves MFMA vs W read directly from pre-converted bf16 global (32 KB, L1-hot).
// (v3 reg-preload of W REGRESSED: +8 VGPR throttled gather pipelining, occ 75->55%.)
__global__ __launch_bounds__(512) void k_aggemm(
    const uint16_t* __restrict__ hw2, const int* __restrict__ off,
    const int* __restrict__ csrs, const float* __restrict__ inv,
    const int* __restrict__ order,
    const uint16_t* __restrict__ Wbf, const float* __restrict__ bias,
    uint16_t* __restrict__ Out)
{
  __shared__ uint4 S4[32][16];     // [row][chunk], chunk swizzled by row&15
  __shared__ int nid[32];
  const int tid = threadIdx.x;

  // ---- gather phase (identical to k_agg, do_relu=1) ----
  const int group = tid >> 4;
  const int node = order[blockIdx.x * 32 + group];
  const int c = (tid & 15) * 8;
  if ((tid & 15) == 0) nid[group] = node;
  const uint16_t* rowp = hw2 + c;

  uint4 sv = *(const uint4*)(rowp + (size_t)node * HH);
  float a[8] = {0.f, 0.f, 0.f, 0.f, 0.f, 0.f, 0.f, 0.f};
  addrow(a, sv);

  int e0 = off[node], e1 = off[node + 1];
  int e = e0;
  for (; e + 4 <= e1; e += 4) {
    int s0 = csrs[e + 0], s1 = csrs[e + 1], s2 = csrs[e + 2], s3 = csrs[e + 3];
    uint4 v0 = *(const uint4*)(rowp + (size_t)s0 * HH);
    uint4 v1 = *(const uint4*)(rowp + (size_t)s1 * HH);
    uint4 v2 = *(const uint4*)(rowp + (size_t)s2 * HH);
    uint4 v3 = *(const uint4*)(rowp + (size_t)s3 * HH);
    addrow(a, v0); addrow(a, v1); addrow(a, v2); addrow(a, v3);
  }
  for (; e < e1; ++e) {
    int s = csrs[e];
    uint4 v = *(const uint4*)(rowp + (size_t)s * HH);
    addrow(a, v);
  }
  float invd = inv[node];
#pragma unroll
  for (int j = 0; j < 8; ++j) a[j] = fmaxf(a[j] * invd, 0.f);
  {
    uint4 o;
    o.x = f2b(a[0]) | (f2b(a[1]) << 16);
    o.y = f2b(a[2]) | (f2b(a[3]) << 16);
    o.z = f2b(a[4]) | (f2b(a[5]) << 16);
    o.w = f2b(a[6]) | (f2b(a[7]) << 16);
    S4[group][(tid & 15) ^ (group & 15)] = o;   // same bf16 rounding as before
  }
  __syncthreads();

  // ---- GEMM phase: wave w computes out-cols [w*16, w*16+16) for all 32 rows ----
  const int lane = tid & 63;
  const int wave = tid >> 6;
  const int lrow = lane & 15;
  const int quad = lane >> 4;
  const int lk = quad * 8;
  const uint16_t* wrow = Wbf + (size_t)(wave * 16 + lrow) * HH;

  floatx4 acc0 = (floatx4){0.f, 0.f, 0.f, 0.f};
  floatx4 acc1 = (floatx4){0.f, 0.f, 0.f, 0.f};
#pragma unroll
  for (int ks = 0; ks < 4; ++ks) {
    int ch = (ks * 4 + quad) ^ lrow;     // swizzled chunk
    bf16x8 a0 = __builtin_bit_cast(bf16x8, S4[lrow][ch]);
    bf16x8 a1 = __builtin_bit_cast(bf16x8, S4[16 + lrow][ch]);
    bf16x8 b  = __builtin_bit_cast(bf16x8, *(const uint4*)(wrow + ks * 32 + lk));
    acc0 = __builtin_amdgcn_mfma_f32_16x16x32_bf16(b, a0, acc0, 0, 0, 0);
    acc1 = __builtin_amdgcn_mfma_f32_16x16x32_bf16(b, a1, acc1, 0, 0, 0);
  }

  float4 b4 = *(const float4*)(bias + wave * 16 + quad * 4);
#pragma unroll
  for (int t = 0; t < 2; ++t) {
    floatx4 ac = t ? acc1 : acc0;
    int row = nid[t * 16 + lrow];
    float sc = inv[row];
    float v0 = (ac[0] + b4.x) * sc;
    float v1 = (ac[1] + b4.y) * sc;
    float v2 = (ac[2] + b4.z) * sc;
    float v3 = (ac[3] + b4.w) * sc;
    uint2 o;
    o.x = f2b(v0) | (f2b(v1) << 16);
    o.y = f2b(v2) | (f2b(v3) << 16);
    *(uint2*)(Out + (size_t)row * HH + wave * 16 + quad * 4) = o;
  }
}

// ================= fused final agg + global_add_pool =================
__global__ __launch_bounds__(256) void k_aggpool(
    const uint16_t* __restrict__ hw2, const int* __restrict__ off,
    const int* __restrict__ csrs, const float* __restrict__ inv,
    const int* __restrict__ batch,
    float* __restrict__ pooled)
{
  __shared__ float red[16][132];
  __shared__ int gid[16];
  const int tid = threadIdx.x;
  const int slot = tid >> 4;
  const int node = blockIdx.x * 16 + slot;    // NN = 6250*16 exactly
  const int c = (tid & 15) * 8;
  if ((tid & 15) == 0) gid[slot] = batch[node];
  const uint16_t* rowp = hw2 + c;

  uint4 sv = *(const uint4*)(rowp + (size_t)node * HH);
  float a[8] = {0.f, 0.f, 0.f, 0.f, 0.f, 0.f, 0.f, 0.f};
  addrow(a, sv);

  int e0 = off[node], e1 = off[node + 1];
  int e = e0;
  for (; e + 4 <= e1; e += 4) {
    int s0 = csrs[e + 0], s1 = csrs[e + 1], s2 = csrs[e + 2], s3 = csrs[e + 3];
    uint4 v0 = *(const uint4*)(rowp + (size_t)s0 * HH);
    uint4 v1 = *(const uint4*)(rowp + (size_t)s1 * HH);
    uint4 v2 = *(const uint4*)(rowp + (size_t)s2 * HH);
    uint4 v3 = *(const uint4*)(rowp + (size_t)s3 * HH);
    addrow(a, v0); addrow(a, v1); addrow(a, v2); addrow(a, v3);
  }
  for (; e < e1; ++e) {
    int s = csrs[e];
    uint4 v = *(const uint4*)(rowp + (size_t)s * HH);
    addrow(a, v);
  }
  float invd = inv[node];
#pragma unroll
  for (int j = 0; j < 8; ++j) a[j] *= invd;
  *(float4*)&red[slot][c]     = make_float4(a[0], a[1], a[2], a[3]);
  *(float4*)&red[slot][c + 4] = make_float4(a[4], a[5], a[6], a[7]);
  __syncthreads();

  if (tid < 128) {
    int g = gid[0];
    float run = red[0][tid];
    for (int r = 1; r < 16; ++r) {
      int gg = gid[r];
      if (gg != g) {
        unsafeAtomicAdd(&pooled[(size_t)g * HH + tid], run);
        run = 0.f; g = gg;
      }
      run += red[r][tid];
    }
    unsafeAtomicAdd(&pooled[(size_t)g * HH + tid], run);
  }
}

// ================= decoder: one block per graph, reads pooled f32 =================
__global__ __launch_bounds__(256) void k_dec(
    const float* __restrict__ pooled,
    const float* __restrict__ w1, const float* __restrict__ b1,
    const float* __restrict__ w2, const float* __restrict__ b2,
    float* __restrict__ out)
{
  __shared__ float p[128], tmpv[128];
  int g = blockIdx.x;
  int tid = threadIdx.x;
  if (tid < 128) p[tid] = pooled[(size_t)g * HH + tid];
  __syncthreads();
  if (tid < 128) {
    float acc1 = b1[tid];
    for (int k = 0; k < 128; ++k) acc1 += p[k] * w1[k * 128 + tid];
    tmpv[tid] = fmaxf(acc1, 0.f);
  }
  __syncthreads();
  if (tid < 10) {
    float o = b2[tid];
    for (int k = 0; k < 128; ++k) o += tmpv[k] * w2[k * 10 + tid];
    out[g * 10 + tid] = o;
  }
}

extern "C" void kernel_launch(void* const* d_in, const int* in_sizes, int n_in,
                              void* d_out, int out_size, void* d_ws, size_t ws_size,
                              hipStream_t stream) {
  const float* x       = (const float*)d_in[0];
  const int*   eidx    = (const int*)d_in[1];
  const int*   src     = eidx;            // edge_index[0]
  const int*   dst     = eidx + NE;       // edge_index[1]
  const int*   batch   = (const int*)d_in[3];
  const float* enc_w1  = (const float*)d_in[4];
  const float* enc_b1  = (const float*)d_in[5];
  const float* enc_w2  = (const float*)d_in[6];
  const float* enc_b2  = (const float*)d_in[7];
  const float* conv_w  = (const float*)d_in[8];
  const float* conv_b  = (const float*)d_in[9];
  const float* dec_w1  = (const float*)d_in[10];
  const float* dec_b1  = (const float*)d_in[11];
  const float* dec_w2  = (const float*)d_in[12];
  const float* dec_b2  = (const float*)d_in[13];
  float* out = (float*)d_out;

  char* ws = (char*)d_ws;
  size_t o = 0;
  auto alloc = [&](size_t bytes) -> char* {
    char* p = ws + o;
    o += (bytes + 255) & ~(size_t)255;
    return p;
  };
  int*      off     = (int*)alloc((size_t)(NN + 1) * 4);
  int*      csrs    = (int*)alloc((size_t)NE * 4);
  float*    inv     = (float*)alloc((size_t)NN * 4);
  int*      blkcntA = (int*)alloc((size_t)NBLK * NB * 4);   // TRANSPOSED [t*NBLK+r]
  int*      poffA   = (int*)alloc((size_t)NBLK * NB * 4);   // TRANSPOSED
  int*      blkcntB = (int*)alloc((size_t)NBLK * NB * 4);   // TRANSPOSED
  int*      poffB   = (int*)alloc((size_t)NBLK * NB * 4);   // TRANSPOSED
  int*      gbaseA  = (int*)alloc((size_t)(NB + 1) * 4);
  int*      gbaseB  = (int*)alloc((size_t)(NB + 1) * 4);
  int*      dhist2  = (int*)alloc((size_t)NB * 64 * 4);
  int*      dcur    = (int*)alloc(64 * 4);
  int*      order   = (int*)alloc((size_t)NN * 4);
  int*      gstart  = (int*)alloc((size_t)(NG + 1) * 4);
  float*    pooled  = (float*)alloc((size_t)NG * HH * 4);
  uint16_t* wbf     = (uint16_t*)alloc((size_t)2 * 16384 * 2);   // conv1,2 bf16 [n][k]
  uint32_t* pairB   = (uint32_t*)alloc((size_t)NE * 4);          // live while enc1 writes buf1
  uint16_t* buf0    = (uint16_t*)alloc((size_t)NN * HH * 2);
  uint16_t* buf1    = (uint16_t*)alloc((size_t)NN * HH * 2);
  uint2*    pairsA  = (uint2*)buf1;   // alias: dead after placeB, before enc1 writes buf1

  // L1: cntA || wprep || pooled zero || blkcntB zero (NBZ=300 blocks, full 76,636 ints)
  k_front<<<dim3(NBLK + 128 + 32 + NBZ), dim3(256), 0, stream>>>(src, blkcntA, blkcntB,
                                                                 conv_w, wbf, pooled);
  // L2: scan A
  k_scan<<<dim3(1), dim3(256), 0, stream>>>(blkcntA, poffA, gbaseA, off, 0);
  // L3: placeA (src-bucket sort) + fused cntB
  k_placeA<<<dim3(NBLK), dim3(256), 0, stream>>>(src, dst, poffA, gbaseA, pairsA, blkcntB);
  // L4: scan B (+ off[NN]=NE)
  k_scan<<<dim3(1), dim3(256), 0, stream>>>(blkcntB, poffB, gbaseB, off, 1);
  // L5: placeB (dst-bucket sort, packed)
  k_placeB<<<dim3(NBLK), dim3(256), 0, stream>>>(pairsA, poffB, gbaseB, pairB);
  // L6: bucket_sort || enc1 GEMM
  k_sortenc<<<dim3(GB + NB), dim3(256), 0, stream>>>(pairB, gbaseB, batch, off, csrs,
                                                     dhist2, gstart,
                                                     x, enc_w1, enc_b1, buf1);
  // L7: dscan || inv
  k_dinv<<<dim3(1 + NBK), dim3(256), 0, stream>>>(dhist2, dcur, off, inv);
  // L8: dual GEMM (enc2 + conv0 + prescale) || dplace
  k_dualplace<<<dim3(GB + NBK), dim3(256), 0, stream>>>(buf1, enc_w2, enc_b2,
                                                        conv_w + 0 * 16384, conv_b + 0,
                                                        inv, buf0, off, dcur, order);

  // GCN layers: fused [agg + conv GEMM + prescale] x2, then fused [agg + pool]
  const int FB = NN / 32;          // 3125 (32 nodes/block, 512 threads)
  const int AB = NN / 16;          // 6250
  k_aggemm<<<dim3(FB), dim3(512), 0, stream>>>(buf0, off, csrs, inv, order,
                                               wbf, conv_b + 128, buf1);
  k_aggemm<<<dim3(FB), dim3(512), 0, stream>>>(buf1, off, csrs, inv, order,
                                               wbf + 16384, conv_b + 256, buf0);
  k_aggpool<<<dim3(AB), dim3(256), 0, stream>>>(buf0, off, csrs, inv, batch, pooled);

  // decoder
  k_dec<<<dim3(NG), dim3(256), 0, stream>>>(pooled, dec_w1, dec_b1, dec_w2, dec_b2, out);
}

// Round 10
// 478.100 us; speedup vs baseline: 1.1073x; 1.1073x over previous
//
#include <hip/hip_runtime.h>
#include <hip/hip_bf16.h>
#include <cstdint>
#include <cstddef>

#define NN 100000      // nodes
#define NE 1600000     // edges
#define HH 128         // hidden dim
#define NG 256         // graphs

#define NB 196         // buckets (512 nodes each; 196*512 = 100352 >= NN)
#define BSH 9          // bucket shift
#define BMSK 511
#define CHUNK 4096     // edges per binning block
#define NBLK 391       // ceil(NE / CHUNK)
#define GB 782         // GEMM blocks: ceil(NN/128)
#define NBK 391        // ceil(NN/256)

typedef __bf16 bf16x8 __attribute__((ext_vector_type(8)));
typedef float floatx4 __attribute__((ext_vector_type(4)));

__device__ __forceinline__ uint32_t f2b(float f) {
  union { float f; uint32_t u; } v; v.f = f;
  uint32_t u = v.u;
  return (u + 0x7FFFu + ((u >> 16) & 1u)) >> 16;   // RNE to bf16 (raw 16 bits)
}
// bf16 lane unpack: low half = u<<16, high half = u & 0xFFFF0000 (1 VALU op each)
__device__ __forceinline__ float blo(uint32_t u) {
  union { uint32_t u; float f; } v; v.u = u << 16;
  return v.f;
}
__device__ __forceinline__ float bhi(uint32_t u) {
  union { uint32_t u; float f; } v; v.u = u & 0xFFFF0000u;
  return v.f;
}
__device__ __forceinline__ void addrow(float* a, uint4 v) {
  a[0] += blo(v.x); a[1] += bhi(v.x);
  a[2] += blo(v.y); a[3] += bhi(v.y);
  a[4] += blo(v.z); a[5] += bhi(v.z);
  a[6] += blo(v.w); a[7] += bhi(v.w);
}

__device__ __forceinline__ void stage_w(uint16_t (*Wt)[136], const float* __restrict__ W,
                                        int tid) {
  for (int it = 0; it < 16; ++it) {
    int idx = tid + it * 256;
    int n = idx & 127;
    int k0 = (idx >> 7) * 4;
    uint2 wv;
    wv.x = f2b(W[(k0 + 0) * 128 + n]) | (f2b(W[(k0 + 1) * 128 + n]) << 16);
    wv.y = f2b(W[(k0 + 2) * 128 + n]) | (f2b(W[(k0 + 3) * 128 + n]) << 16);
    *(uint2*)&Wt[n][k0] = wv;
  }
}

// ================= L1: cntA || wprep || pooled zero =================
// blkcnt layouts are TRANSPOSED: blkcnt[t*NBLK + r] (column-major) so the scan
// kernel reads each bucket's chunk-counts contiguously.
__global__ __launch_bounds__(256) void k_front(const int* __restrict__ src,
                                               int* __restrict__ blkcntA,
                                               const float* __restrict__ conv_w,
                                               uint16_t* __restrict__ wbf,
                                               float* __restrict__ pooled) {
  int t = threadIdx.x;
  if (blockIdx.x < NBLK) {
    __shared__ int h[NB];
    if (t < NB) h[t] = 0;
    __syncthreads();
    int base = blockIdx.x * CHUNK, end = min(base + CHUNK, NE);
    for (int i = base + t; i < end; i += 256) atomicAdd(&h[src[i] >> BSH], 1);
    __syncthreads();
    if (t < NB) blkcntA[t * NBLK + blockIdx.x] = h[t];
  } else if (blockIdx.x < NBLK + 128) {
    // conv layers 1,2 fp32 [k][n] -> bf16 [n][k]; same f2b rounding as stage_w
    int idx = (blockIdx.x - NBLK) * 256 + t;   // 0..32767
    int l = idx >> 14;
    int n = (idx >> 7) & 127;
    int k = idx & 127;
    wbf[idx] = (uint16_t)f2b(conv_w[(l + 1) * 16384 + k * 128 + n]);
  } else {
    int i = ((blockIdx.x - NBLK - 128) * 256 + t) * 4;   // 32 blocks x 1024 floats
    if (i < NG * HH) *(float4*)&pooled[i] = make_float4(0.f, 0.f, 0.f, 0.f);
  }
}

// ================= cntB: dst-bucket histogram via LDS (r9's global-atomic fusion
// REGRESSED placeA 11->73 us: 1.6M scattered global atomics, 21-way line contention) =====
__global__ __launch_bounds__(256) void k_cntB(const uint2* __restrict__ pairs,
                                              int* __restrict__ blkcnt) {
  __shared__ int h[NB];
  int t = threadIdx.x;
  if (t < NB) h[t] = 0;
  __syncthreads();
  int base = blockIdx.x * CHUNK, end = min(base + CHUNK, NE);
  for (int i = base + t; i < end; i += 256) atomicAdd(&h[pairs[i].y >> BSH], 1);
  __syncthreads();
  if (t < NB) blkcnt[t * NBLK + blockIdx.x] = h[t];   // transposed
}

// merged column-scan + global-scan over TRANSPOSED blkcnt: 1 block.
// 8-wide blocked loads so the accumulation pipelines.
__global__ void k_scan(const int* __restrict__ blkcnt, int* __restrict__ poff,
                       int* __restrict__ gbase, int* __restrict__ off, int set_off) {
  __shared__ int s[256];
  int t = threadIdx.x;
  int tot = 0;
  if (t < NB) {
    const int* col = blkcnt + (size_t)t * NBLK;
    int* pcol = poff + (size_t)t * NBLK;
    int r0 = 0;
    for (; r0 + 8 <= NBLK; r0 += 8) {
      int v[8];
#pragma unroll
      for (int j = 0; j < 8; ++j) v[j] = col[r0 + j];
#pragma unroll
      for (int j = 0; j < 8; ++j) { pcol[r0 + j] = tot; tot += v[j]; }
    }
    for (; r0 < NBLK; ++r0) { pcol[r0] = tot; tot += col[r0]; }
  }
  s[t] = (t < NB) ? tot : 0;
  __syncthreads();
  for (int d = 1; d < 256; d <<= 1) {
    int v = (t >= d) ? s[t - d] : 0;
    __syncthreads();
    s[t] += v;
    __syncthreads();
  }
  if (t < NB) gbase[t] = s[t] - tot;
  if (t == 0) { gbase[NB] = NE; if (set_off) off[NN] = NE; }
}

// ================= placeA: src-bucket sort (no fused counting) =================
__global__ __launch_bounds__(256) void k_placeA(const int* __restrict__ src,
                                                const int* __restrict__ dst,
                                                const int* __restrict__ poff,
                                                const int* __restrict__ gbase,
                                                uint2* __restrict__ pairs) {
  __shared__ int cur[NB];
  int t = threadIdx.x;
  if (t < NB) cur[t] = poff[(size_t)t * NBLK + blockIdx.x] + gbase[t];
  __syncthreads();
  int base = blockIdx.x * CHUNK, end = min(base + CHUNK, NE);
  for (int i = base + t; i < end; i += 256) {
    int s = src[i], d = dst[i];
    int p = atomicAdd(&cur[s >> BSH], 1);
    pairs[p] = make_uint2((unsigned)s, (unsigned)d);
  }
}

__global__ __launch_bounds__(256) void k_placeB(const uint2* __restrict__ pairs,
                                                const int* __restrict__ poff,
                                                const int* __restrict__ gbase,
                                                uint32_t* __restrict__ outb) {
  __shared__ int cur[NB];
  int t = threadIdx.x;
  if (t < NB) cur[t] = poff[(size_t)t * NBLK + blockIdx.x] + gbase[t];
  __syncthreads();
  int base = blockIdx.x * CHUNK, end = min(base + CHUNK, NE);
  for (int i = base + t; i < end; i += 256) {
    uint2 v = pairs[i];
    int p = atomicAdd(&cur[v.y >> BSH], 1);
    outb[p] = v.x | ((v.y & (unsigned)BMSK) << 17);
  }
}

// ================= L6: bucket_sort || enc1 GEMM =================
__global__ __launch_bounds__(256) void k_sortenc(
    const uint32_t* __restrict__ pairbuf, const int* __restrict__ gbase,
    const int* __restrict__ batch,
    int* __restrict__ off, int* __restrict__ csrs,
    int* __restrict__ dhist2, int* __restrict__ gstart,
    const float* __restrict__ A32, const float* __restrict__ W,
    const float* __restrict__ bias, uint16_t* __restrict__ Out)
{
  __shared__ char smraw[34816];
  const int tid = threadIdx.x;

  if (blockIdx.x < GB) {
    // ---------------- enc1 GEMM ----------------
    auto Wt = (uint16_t(*)[136])smraw;
    stage_w(Wt, W, tid);
    __syncthreads();

    const int lane = tid & 63;
    const int wave = tid >> 6;
    const int lrow = lane & 15;
    const int quad = lane >> 4;
    const int lk = quad * 8;
    const int row0 = blockIdx.x * 128 + wave * 32;

    floatx4 acc[2][8];
#pragma unroll
    for (int t = 0; t < 2; ++t)
#pragma unroll
      for (int n = 0; n < 8; ++n)
        acc[t][n] = (floatx4){0.f, 0.f, 0.f, 0.f};

#pragma unroll
    for (int ks = 0; ks < 4; ++ks) {
      bf16x8 a[2];
#pragma unroll
      for (int t = 0; t < 2; ++t) {
        int r = row0 + t * 16 + lrow;
        uint4 tmp = {0u, 0u, 0u, 0u};
        if (r < NN) {
          float4 f0 = *(const float4*)(A32 + (size_t)r * HH + ks * 32 + lk);
          float4 f1 = *(const float4*)(A32 + (size_t)r * HH + ks * 32 + lk + 4);
          tmp.x = f2b(f0.x) | (f2b(f0.y) << 16);
          tmp.y = f2b(f0.z) | (f2b(f0.w) << 16);
          tmp.z = f2b(f1.x) | (f2b(f1.y) << 16);
          tmp.w = f2b(f1.z) | (f2b(f1.w) << 16);
        }
        a[t] = __builtin_bit_cast(bf16x8, tmp);
      }
#pragma unroll
      for (int n = 0; n < 8; ++n) {
        bf16x8 b = __builtin_bit_cast(bf16x8, *(const uint4*)&Wt[n * 16 + lrow][ks * 32 + lk]);
        acc[0][n] = __builtin_amdgcn_mfma_f32_16x16x32_bf16(b, a[0], acc[0][n], 0, 0, 0);
        acc[1][n] = __builtin_amdgcn_mfma_f32_16x16x32_bf16(b, a[1], acc[1][n], 0, 0, 0);
      }
    }

    float4 b4[8];
#pragma unroll
    for (int n = 0; n < 8; ++n) b4[n] = *(const float4*)(bias + n * 16 + quad * 4);

#pragma unroll
    for (int t = 0; t < 2; ++t) {
      int row = row0 + t * 16 + lrow;
      if (row < NN) {
        uint16_t* orow = Out + (size_t)row * HH;
#pragma unroll
        for (int n = 0; n < 8; ++n) {
          float v0 = fmaxf(acc[t][n][0] + b4[n].x, 0.f);
          float v1 = fmaxf(acc[t][n][1] + b4[n].y, 0.f);
          float v2 = fmaxf(acc[t][n][2] + b4[n].z, 0.f);
          float v3 = fmaxf(acc[t][n][3] + b4[n].w, 0.f);
          uint2 o;
          o.x = f2b(v0) | (f2b(v1) << 16);
          o.y = f2b(v2) | (f2b(v3) << 16);
          *(uint2*)(orow + n * 16 + quad * 4) = o;
        }
      }
    }
  } else {
    // ---------------- bucket_sort ----------------
    int* cnt  = (int*)smraw;        // 512
    int* loff = cnt + 512;          // 512
    int* psum = loff + 512;         // 256
    int b = blockIdx.x - GB;
    cnt[tid] = 0; cnt[tid + 256] = 0;
    __syncthreads();
    int s0 = gbase[b], s1 = gbase[b + 1];
    for (int i = s0 + tid; i < s1; i += 256)
      atomicAdd(&cnt[pairbuf[i] >> 17], 1);
    __syncthreads();
    int a0 = cnt[2 * tid], a1 = cnt[2 * tid + 1];
    int s = a0 + a1;
    psum[tid] = s;
    __syncthreads();
    for (int d = 1; d < 256; d <<= 1) {
      int v = (tid >= d) ? psum[tid - d] : 0;
      __syncthreads();
      psum[tid] += v;
      __syncthreads();
    }
    int excl = psum[tid] - s;
    loff[2 * tid] = excl;
    loff[2 * tid + 1] = excl + a0;
    __syncthreads();
    int* h64 = psum;               // psum dead after excl computed
    if (tid < 64) h64[tid] = 0;
    __syncthreads();
#pragma unroll
    for (int k = 0; k < 2; ++k) {
      int i = tid + k * 256;
      int node = b * 512 + i;
      if (node < NN) {
        off[node] = s0 + loff[i];
        int d = cnt[i]; if (d > 63) d = 63;
        atomicAdd(&h64[d], 1);
      }
    }
    // gstart for this block's node range (batch sorted)
    {
      int n0 = b * 512, n1 = min(n0 + 512, NN);
      for (int i = n0 + tid; i < n1; i += 256) {
        int bb = batch[i];
        if (i == 0) { for (int g = 0; g <= bb; ++g) gstart[g] = 0; }
        else { int aa = batch[i - 1]; for (int g = aa + 1; g <= bb; ++g) gstart[g] = i; }
        if (i == NN - 1) { for (int g = bb + 1; g <= NG; ++g) gstart[g] = NN; }
      }
    }
    __syncthreads();
    if (tid < 64) dhist2[b * 64 + tid] = h64[tid];
    cnt[tid] = loff[tid]; cnt[tid + 256] = loff[tid + 256];   // counters -> cursors
    __syncthreads();
    for (int i = s0 + tid; i < s1; i += 256) {
      uint32_t v = pairbuf[i];
      int p = atomicAdd(&cnt[v >> 17], 1);
      csrs[s0 + p] = (int)(v & 0x1FFFFu);
    }
  }
}

// ================= L7: dscan (block 0) || inv from off-diffs =================
__global__ __launch_bounds__(256) void k_dinv(const int* __restrict__ dhist2,
                                              int* __restrict__ dcur,
                                              const int* __restrict__ off,
                                              float* __restrict__ inv) {
  if (blockIdx.x == 0) {
    int t = threadIdx.x;
    if (t < 64) {
      int sum = 0;
      for (int r = 0; r < NB; ++r) sum += dhist2[r * 64 + (63 - t)];
      int v = sum;
      for (int d = 1; d < 64; d <<= 1) { int u = __shfl_up(v, d); if (t >= d) v += u; }
      dcur[63 - t] = v - sum;
    }
  } else {
    int i = (blockIdx.x - 1) * 256 + threadIdx.x;
    if (i < NN) inv[i] = rsqrtf((float)(off[i + 1] - off[i]) + 1.0f);
  }
}

// ================= L8: fused dual GEMM (enc2+conv0, prescale) || dplace =================
__global__ __launch_bounds__(256) void k_dualplace(
    const uint16_t* __restrict__ A16,
    const float* __restrict__ Wa, const float* __restrict__ ba,
    const float* __restrict__ Wb, const float* __restrict__ bb,
    const float* __restrict__ scale, uint16_t* __restrict__ Out,
    const int* __restrict__ off, int* __restrict__ dcur, int* __restrict__ order)
{
  __shared__ uint16_t Wt[128][136];
  __shared__ uint16_t tile[128][136];
  const int tid = threadIdx.x;

  if (blockIdx.x < GB) {
    // ---------------- dual GEMM ----------------
    stage_w(Wt, Wa, tid);
    __syncthreads();

    const int lane = tid & 63;
    const int wave = tid >> 6;
    const int lrow = lane & 15;
    const int quad = lane >> 4;
    const int lk = quad * 8;
    const int row0 = blockIdx.x * 128 + wave * 32;
    const int trow0 = wave * 32;

    floatx4 acc[2][8];
#pragma unroll
    for (int t = 0; t < 2; ++t)
#pragma unroll
      for (int n = 0; n < 8; ++n)
        acc[t][n] = (floatx4){0.f, 0.f, 0.f, 0.f};

    // phase 1: global A -> C1 (swapped layout)
#pragma unroll
    for (int ks = 0; ks < 4; ++ks) {
      bf16x8 a[2];
#pragma unroll
      for (int t = 0; t < 2; ++t) {
        int r = row0 + t * 16 + lrow;
        uint4 tmp = {0u, 0u, 0u, 0u};
        if (r < NN) tmp = *(const uint4*)(A16 + (size_t)r * HH + ks * 32 + lk);
        a[t] = __builtin_bit_cast(bf16x8, tmp);
      }
#pragma unroll
      for (int n = 0; n < 8; ++n) {
        bf16x8 b = __builtin_bit_cast(bf16x8, *(const uint4*)&Wt[n * 16 + lrow][ks * 32 + lk]);
        acc[0][n] = __builtin_amdgcn_mfma_f32_16x16x32_bf16(b, a[0], acc[0][n], 0, 0, 0);
        acc[1][n] = __builtin_amdgcn_mfma_f32_16x16x32_bf16(b, a[1], acc[1][n], 0, 0, 0);
      }
    }

    // epilogue 1 -> LDS tile (bias, no relu)
    {
      float4 b4[8];
#pragma unroll
      for (int n = 0; n < 8; ++n) b4[n] = *(const float4*)(ba + n * 16 + quad * 4);
#pragma unroll
      for (int t = 0; t < 2; ++t) {
        int trow = trow0 + t * 16 + lrow;
#pragma unroll
        for (int n = 0; n < 8; ++n) {
          uint2 o;
          o.x = f2b(acc[t][n][0] + b4[n].x) | (f2b(acc[t][n][1] + b4[n].y) << 16);
          o.y = f2b(acc[t][n][2] + b4[n].z) | (f2b(acc[t][n][3] + b4[n].w) << 16);
          *(uint2*)&tile[trow][n * 16 + quad * 4] = o;
        }
      }
    }
    __syncthreads();
    stage_w(Wt, Wb, tid);
#pragma unroll
    for (int t = 0; t < 2; ++t)
#pragma unroll
      for (int n = 0; n < 8; ++n)
        acc[t][n] = (floatx4){0.f, 0.f, 0.f, 0.f};
    __syncthreads();

    // phase 2: LDS tile A -> C2
#pragma unroll
    for (int ks = 0; ks < 4; ++ks) {
      bf16x8 a[2];
#pragma unroll
      for (int t = 0; t < 2; ++t)
        a[t] = __builtin_bit_cast(bf16x8,
                 *(const uint4*)&tile[trow0 + t * 16 + lrow][ks * 32 + lk]);
#pragma unroll
      for (int n = 0; n < 8; ++n) {
        bf16x8 b = __builtin_bit_cast(bf16x8, *(const uint4*)&Wt[n * 16 + lrow][ks * 32 + lk]);
        acc[0][n] = __builtin_amdgcn_mfma_f32_16x16x32_bf16(b, a[0], acc[0][n], 0, 0, 0);
        acc[1][n] = __builtin_amdgcn_mfma_f32_16x16x32_bf16(b, a[1], acc[1][n], 0, 0, 0);
      }
    }

    // epilogue 2 -> global (bias, scale, no relu)
    {
      float4 b4[8];
#pragma unroll
      for (int n = 0; n < 8; ++n) b4[n] = *(const float4*)(bb + n * 16 + quad * 4);
#pragma unroll
      for (int t = 0; t < 2; ++t) {
        int row = row0 + t * 16 + lrow;
        if (row < NN) {
          float sc = scale[row];
          uint16_t* orow = Out + (size_t)row * HH;
#pragma unroll
          for (int n = 0; n < 8; ++n) {
            float v0 = (acc[t][n][0] + b4[n].x) * sc;
            float v1 = (acc[t][n][1] + b4[n].y) * sc;
            float v2 = (acc[t][n][2] + b4[n].z) * sc;
            float v3 = (acc[t][n][3] + b4[n].w) * sc;
            uint2 o;
            o.x = f2b(v0) | (f2b(v1) << 16);
            o.y = f2b(v2) | (f2b(v3) << 16);
            *(uint2*)(orow + n * 16 + quad * 4) = o;
          }
        }
      }
    }
  } else {
    // ---------------- dplace (degree-LPT order) ----------------
    int* h = (int*)Wt;
    int* base = h + 64;
    if (tid < 64) h[tid] = 0;
    __syncthreads();
    int i = (blockIdx.x - GB) * 256 + tid;
    int d = 0, ld = 0;
    if (i < NN) { d = off[i + 1] - off[i]; if (d > 63) d = 63; ld = atomicAdd(&h[d], 1); }
    __syncthreads();
    if (tid < 64) base[tid] = h[tid] ? atomicAdd(&dcur[tid], h[tid]) : 0;
    __syncthreads();
    if (i < NN) order[base[d] + ld] = i;
  }
}

// ================= fused agg + conv GEMM (v2: W from L1-resident global) =================
// 512 threads = 32 nodes (16 lanes/node). Gather-sum -> XOR-swizzled LDS S-tile ->
// 8 waves MFMA vs W read directly from pre-converted bf16 global (32 KB, L1-hot).
// (v3 reg-preload of W REGRESSED: +8 VGPR throttled gather pipelining, occ 75->55%.)
__global__ __launch_bounds__(512) void k_aggemm(
    const uint16_t* __restrict__ hw2, const int* __restrict__ off,
    const int* __restrict__ csrs, const float* __restrict__ inv,
    const int* __restrict__ order,
    const uint16_t* __restrict__ Wbf, const float* __restrict__ bias,
    uint16_t* __restrict__ Out)
{
  __shared__ uint4 S4[32][16];     // [row][chunk], chunk swizzled by row&15
  __shared__ int nid[32];
  const int tid = threadIdx.x;

  // ---- gather phase (identical to k_agg, do_relu=1) ----
  const int group = tid >> 4;
  const int node = order[blockIdx.x * 32 + group];
  const int c = (tid & 15) * 8;
  if ((tid & 15) == 0) nid[group] = node;
  const uint16_t* rowp = hw2 + c;

  uint4 sv = *(const uint4*)(rowp + (size_t)node * HH);
  float a[8] = {0.f, 0.f, 0.f, 0.f, 0.f, 0.f, 0.f, 0.f};
  addrow(a, sv);

  int e0 = off[node], e1 = off[node + 1];
  int e = e0;
  for (; e + 4 <= e1; e += 4) {
    int s0 = csrs[e + 0], s1 = csrs[e + 1], s2 = csrs[e + 2], s3 = csrs[e + 3];
    uint4 v0 = *(const uint4*)(rowp + (size_t)s0 * HH);
    uint4 v1 = *(const uint4*)(rowp + (size_t)s1 * HH);
    uint4 v2 = *(const uint4*)(rowp + (size_t)s2 * HH);
    uint4 v3 = *(const uint4*)(rowp + (size_t)s3 * HH);
    addrow(a, v0); addrow(a, v1); addrow(a, v2); addrow(a, v3);
  }
  for (; e < e1; ++e) {
    int s = csrs[e];
    uint4 v = *(const uint4*)(rowp + (size_t)s * HH);
    addrow(a, v);
  }
  float invd = inv[node];
#pragma unroll
  for (int j = 0; j < 8; ++j) a[j] = fmaxf(a[j] * invd, 0.f);
  {
    uint4 o;
    o.x = f2b(a[0]) | (f2b(a[1]) << 16);
    o.y = f2b(a[2]) | (f2b(a[3]) << 16);
    o.z = f2b(a[4]) | (f2b(a[5]) << 16);
    o.w = f2b(a[6]) | (f2b(a[7]) << 16);
    S4[group][(tid & 15) ^ (group & 15)] = o;   // same bf16 rounding as before
  }
  __syncthreads();

  // ---- GEMM phase: wave w computes out-cols [w*16, w*16+16) for all 32 rows ----
  const int lane = tid & 63;
  const int wave = tid >> 6;
  const int lrow = lane & 15;
  const int quad = lane >> 4;
  const int lk = quad * 8;
  const uint16_t* wrow = Wbf + (size_t)(wave * 16 + lrow) * HH;

  floatx4 acc0 = (floatx4){0.f, 0.f, 0.f, 0.f};
  floatx4 acc1 = (floatx4){0.f, 0.f, 0.f, 0.f};
#pragma unroll
  for (int ks = 0; ks < 4; ++ks) {
    int ch = (ks * 4 + quad) ^ lrow;     // swizzled chunk
    bf16x8 a0 = __builtin_bit_cast(bf16x8, S4[lrow][ch]);
    bf16x8 a1 = __builtin_bit_cast(bf16x8, S4[16 + lrow][ch]);
    bf16x8 b  = __builtin_bit_cast(bf16x8, *(const uint4*)(wrow + ks * 32 + lk));
    acc0 = __builtin_amdgcn_mfma_f32_16x16x32_bf16(b, a0, acc0, 0, 0, 0);
    acc1 = __builtin_amdgcn_mfma_f32_16x16x32_bf16(b, a1, acc1, 0, 0, 0);
  }

  float4 b4 = *(const float4*)(bias + wave * 16 + quad * 4);
#pragma unroll
  for (int t = 0; t < 2; ++t) {
    floatx4 ac = t ? acc1 : acc0;
    int row = nid[t * 16 + lrow];
    float sc = inv[row];
    float v0 = (ac[0] + b4.x) * sc;
    float v1 = (ac[1] + b4.y) * sc;
    float v2 = (ac[2] + b4.z) * sc;
    float v3 = (ac[3] + b4.w) * sc;
    uint2 o;
    o.x = f2b(v0) | (f2b(v1) << 16);
    o.y = f2b(v2) | (f2b(v3) << 16);
    *(uint2*)(Out + (size_t)row * HH + wave * 16 + quad * 4) = o;
  }
}

// ================= fused final agg + global_add_pool =================
__global__ __launch_bounds__(256) void k_aggpool(
    const uint16_t* __restrict__ hw2, const int* __restrict__ off,
    const int* __restrict__ csrs, const float* __restrict__ inv,
    const int* __restrict__ batch,
    float* __restrict__ pooled)
{
  __shared__ float red[16][132];
  __shared__ int gid[16];
  const int tid = threadIdx.x;
  const int slot = tid >> 4;
  const int node = blockIdx.x * 16 + slot;    // NN = 6250*16 exactly
  const int c = (tid & 15) * 8;
  if ((tid & 15) == 0) gid[slot] = batch[node];
  const uint16_t* rowp = hw2 + c;

  uint4 sv = *(const uint4*)(rowp + (size_t)node * HH);
  float a[8] = {0.f, 0.f, 0.f, 0.f, 0.f, 0.f, 0.f, 0.f};
  addrow(a, sv);

  int e0 = off[node], e1 = off[node + 1];
  int e = e0;
  for (; e + 4 <= e1; e += 4) {
    int s0 = csrs[e + 0], s1 = csrs[e + 1], s2 = csrs[e + 2], s3 = csrs[e + 3];
    uint4 v0 = *(const uint4*)(rowp + (size_t)s0 * HH);
    uint4 v1 = *(const uint4*)(rowp + (size_t)s1 * HH);
    uint4 v2 = *(const uint4*)(rowp + (size_t)s2 * HH);
    uint4 v3 = *(const uint4*)(rowp + (size_t)s3 * HH);
    addrow(a, v0); addrow(a, v1); addrow(a, v2); addrow(a, v3);
  }
  for (; e < e1; ++e) {
    int s = csrs[e];
    uint4 v = *(const uint4*)(rowp + (size_t)s * HH);
    addrow(a, v);
  }
  float invd = inv[node];
#pragma unroll
  for (int j = 0; j < 8; ++j) a[j] *= invd;
  *(float4*)&red[slot][c]     = make_float4(a[0], a[1], a[2], a[3]);
  *(float4*)&red[slot][c + 4] = make_float4(a[4], a[5], a[6], a[7]);
  __syncthreads();

  if (tid < 128) {
    int g = gid[0];
    float run = red[0][tid];
    for (int r = 1; r < 16; ++r) {
      int gg = gid[r];
      if (gg != g) {
        unsafeAtomicAdd(&pooled[(size_t)g * HH + tid], run);
        run = 0.f; g = gg;
      }
      run += red[r][tid];
    }
    unsafeAtomicAdd(&pooled[(size_t)g * HH + tid], run);
  }
}

// ================= decoder: one block per graph, reads pooled f32 =================
__global__ __launch_bounds__(256) void k_dec(
    const float* __restrict__ pooled,
    const float* __restrict__ w1, const float* __restrict__ b1,
    const float* __restrict__ w2, const float* __restrict__ b2,
    float* __restrict__ out)
{
  __shared__ float p[128], tmpv[128];
  int g = blockIdx.x;
  int tid = threadIdx.x;
  if (tid < 128) p[tid] = pooled[(size_t)g * HH + tid];
  __syncthreads();
  if (tid < 128) {
    float acc1 = b1[tid];
    for (int k = 0; k < 128; ++k) acc1 += p[k] * w1[k * 128 + tid];
    tmpv[tid] = fmaxf(acc1, 0.f);
  }
  __syncthreads();
  if (tid < 10) {
    float o = b2[tid];
    for (int k = 0; k < 128; ++k) o += tmpv[k] * w2[k * 10 + tid];
    out[g * 10 + tid] = o;
  }
}

extern "C" void kernel_launch(void* const* d_in, const int* in_sizes, int n_in,
                              void* d_out, int out_size, void* d_ws, size_t ws_size,
                              hipStream_t stream) {
  const float* x       = (const float*)d_in[0];
  const int*   eidx    = (const int*)d_in[1];
  const int*   src     = eidx;            // edge_index[0]
  const int*   dst     = eidx + NE;       // edge_index[1]
  const int*   batch   = (const int*)d_in[3];
  const float* enc_w1  = (const float*)d_in[4];
  const float* enc_b1  = (const float*)d_in[5];
  const float* enc_w2  = (const float*)d_in[6];
  const float* enc_b2  = (const float*)d_in[7];
  const float* conv_w  = (const float*)d_in[8];
  const float* conv_b  = (const float*)d_in[9];
  const float* dec_w1  = (const float*)d_in[10];
  const float* dec_b1  = (const float*)d_in[11];
  const float* dec_w2  = (const float*)d_in[12];
  const float* dec_b2  = (const float*)d_in[13];
  float* out = (float*)d_out;

  char* ws = (char*)d_ws;
  size_t o = 0;
  auto alloc = [&](size_t bytes) -> char* {
    char* p = ws + o;
    o += (bytes + 255) & ~(size_t)255;
    return p;
  };
  int*      off     = (int*)alloc((size_t)(NN + 1) * 4);
  int*      csrs    = (int*)alloc((size_t)NE * 4);
  float*    inv     = (float*)alloc((size_t)NN * 4);
  int*      blkcntA = (int*)alloc((size_t)NBLK * NB * 4);   // TRANSPOSED [t*NBLK+r]
  int*      poffA   = (int*)alloc((size_t)NBLK * NB * 4);   // TRANSPOSED
  int*      blkcntB = (int*)alloc((size_t)NBLK * NB * 4);   // TRANSPOSED
  int*      poffB   = (int*)alloc((size_t)NBLK * NB * 4);   // TRANSPOSED
  int*      gbaseA  = (int*)alloc((size_t)(NB + 1) * 4);
  int*      gbaseB  = (int*)alloc((size_t)(NB + 1) * 4);
  int*      dhist2  = (int*)alloc((size_t)NB * 64 * 4);
  int*      dcur    = (int*)alloc(64 * 4);
  int*      order   = (int*)alloc((size_t)NN * 4);
  int*      gstart  = (int*)alloc((size_t)(NG + 1) * 4);
  float*    pooled  = (float*)alloc((size_t)NG * HH * 4);
  uint16_t* wbf     = (uint16_t*)alloc((size_t)2 * 16384 * 2);   // conv1,2 bf16 [n][k]
  uint32_t* pairB   = (uint32_t*)alloc((size_t)NE * 4);          // live while enc1 writes buf1
  uint16_t* buf0    = (uint16_t*)alloc((size_t)NN * HH * 2);
  uint16_t* buf1    = (uint16_t*)alloc((size_t)NN * HH * 2);
  uint2*    pairsA  = (uint2*)buf1;   // alias: dead after placeB, before enc1 writes buf1

  // L1: cntA || wprep || pooled zero
  k_front<<<dim3(NBLK + 128 + 32), dim3(256), 0, stream>>>(src, blkcntA, conv_w, wbf, pooled);
  // L2: scan A
  k_scan<<<dim3(1), dim3(256), 0, stream>>>(blkcntA, poffA, gbaseA, off, 0);
  // L3: placeA (src-bucket sort)
  k_placeA<<<dim3(NBLK), dim3(256), 0, stream>>>(src, dst, poffA, gbaseA, pairsA);
  // L4: cntB (dst-bucket LDS histogram, transposed out)
  k_cntB<<<dim3(NBLK), dim3(256), 0, stream>>>(pairsA, blkcntB);
  // L5: scan B (+ off[NN]=NE)
  k_scan<<<dim3(1), dim3(256), 0, stream>>>(blkcntB, poffB, gbaseB, off, 1);
  // L6: placeB (dst-bucket sort, packed)
  k_placeB<<<dim3(NBLK), dim3(256), 0, stream>>>(pairsA, poffB, gbaseB, pairB);
  // L7: bucket_sort || enc1 GEMM
  k_sortenc<<<dim3(GB + NB), dim3(256), 0, stream>>>(pairB, gbaseB, batch, off, csrs,
                                                     dhist2, gstart,
                                                     x, enc_w1, enc_b1, buf1);
  // L8: dscan || inv
  k_dinv<<<dim3(1 + NBK), dim3(256), 0, stream>>>(dhist2, dcur, off, inv);
  // L9: dual GEMM (enc2 + conv0 + prescale) || dplace
  k_dualplace<<<dim3(GB + NBK), dim3(256), 0, stream>>>(buf1, enc_w2, enc_b2,
                                                        conv_w + 0 * 16384, conv_b + 0,
                                                        inv, buf0, off, dcur, order);

  // GCN layers: fused [agg + conv GEMM + prescale] x2, then fused [agg + pool]
  const int FB = NN / 32;          // 3125 (32 nodes/block, 512 threads)
  const int AB = NN / 16;          // 6250
  k_aggemm<<<dim3(FB), dim3(512), 0, stream>>>(buf0, off, csrs, inv, order,
                                               wbf, conv_b + 128, buf1);
  k_aggemm<<<dim3(FB), dim3(512), 0, stream>>>(buf1, off, csrs, inv, order,
                                               wbf + 16384, conv_b + 256, buf0);
  k_aggpool<<<dim3(AB), dim3(256), 0, stream>>>(buf0, off, csrs, inv, batch, pooled);

  // decoder
  k_dec<<<dim3(NG), dim3(256), 0, stream>>>(pooled, dec_w1, dec_b1, dec_w2, dec_b2, out);
}

// Round 12
// 442.380 us; speedup vs baseline: 1.1967x; 1.0807x over previous
//
#include <hip/hip_runtime.h>
#include <hip/hip_bf16.h>
#include <cstdint>
#include <cstddef>

#define NN 100000      // nodes
#define NE 1600000     // edges
#define HH 128         // hidden dim
#define NG 256         // graphs

#define NB 196         // buckets (512 nodes each; 196*512 = 100352 >= NN)
#define BSH 9          // bucket shift
#define BMSK 511
#define CHUNK 4096     // edges per binning block
#define NBLK 391       // ceil(NE / CHUNK)
#define GB 782         // GEMM blocks: ceil(NN/128)
#define NBK 391        // ceil(NN/256)

typedef __bf16 bf16x8 __attribute__((ext_vector_type(8)));
typedef float floatx4 __attribute__((ext_vector_type(4)));

__device__ __forceinline__ uint32_t f2b(float f) {
  union { float f; uint32_t u; } v; v.f = f;
  uint32_t u = v.u;
  return (u + 0x7FFFu + ((u >> 16) & 1u)) >> 16;   // RNE to bf16 (raw 16 bits)
}
// bf16 lane unpack: low half = u<<16, high half = u & 0xFFFF0000 (1 VALU op each)
__device__ __forceinline__ float blo(uint32_t u) {
  union { uint32_t u; float f; } v; v.u = u << 16;
  return v.f;
}
__device__ __forceinline__ float bhi(uint32_t u) {
  union { uint32_t u; float f; } v; v.u = u & 0xFFFF0000u;
  return v.f;
}
__device__ __forceinline__ void addrow(float* a, uint4 v) {
  a[0] += blo(v.x); a[1] += bhi(v.x);
  a[2] += blo(v.y); a[3] += bhi(v.y);
  a[4] += blo(v.z); a[5] += bhi(v.z);
  a[6] += blo(v.w); a[7] += bhi(v.w);
}

__device__ __forceinline__ void stage_w(uint16_t (*Wt)[136], const float* __restrict__ W,
                                        int tid) {
  for (int it = 0; it < 16; ++it) {
    int idx = tid + it * 256;
    int n = idx & 127;
    int k0 = (idx >> 7) * 4;
    uint2 wv;
    wv.x = f2b(W[(k0 + 0) * 128 + n]) | (f2b(W[(k0 + 1) * 128 + n]) << 16);
    wv.y = f2b(W[(k0 + 2) * 128 + n]) | (f2b(W[(k0 + 3) * 128 + n]) << 16);
    *(uint2*)&Wt[n][k0] = wv;
  }
}

// ================= L1: enc1 GEMM || cntB (dst-bucket histogram) || wprep || pooled0 ======
// The src-sort pass (cntA/scanA/placeA) is DELETED: r2's footprint-halving null +
// r10's counters imply gather reuse is temporal coincidence of same-src reads across
// dst nodes, NOT the ascending-src sweep — so within-node csrs order doesn't matter.
// blkcnt is TRANSPOSED: blkcnt[t*NBLK + r] so the scan reads contiguously.
__global__ __launch_bounds__(256) void k_front(
    const int* __restrict__ dst, int* __restrict__ blkcntB,
    const float* __restrict__ conv_w, uint16_t* __restrict__ wbf,
    float* __restrict__ pooled,
    const float* __restrict__ A32, const float* __restrict__ W,
    const float* __restrict__ bias, uint16_t* __restrict__ Out)
{
  __shared__ char smraw[34816];
  const int tid = threadIdx.x;

  if (blockIdx.x < GB) {
    // ---------------- enc1 GEMM: buf1 = bf16(relu(x @ enc_w1 + enc_b1)) ----------------
    auto Wt = (uint16_t(*)[136])smraw;
    stage_w(Wt, W, tid);
    __syncthreads();

    const int lane = tid & 63;
    const int wave = tid >> 6;
    const int lrow = lane & 15;
    const int quad = lane >> 4;
    const int lk = quad * 8;
    const int row0 = blockIdx.x * 128 + wave * 32;

    floatx4 acc[2][8];
#pragma unroll
    for (int t = 0; t < 2; ++t)
#pragma unroll
      for (int n = 0; n < 8; ++n)
        acc[t][n] = (floatx4){0.f, 0.f, 0.f, 0.f};

#pragma unroll
    for (int ks = 0; ks < 4; ++ks) {
      bf16x8 a[2];
#pragma unroll
      for (int t = 0; t < 2; ++t) {
        int r = row0 + t * 16 + lrow;
        uint4 tmp = {0u, 0u, 0u, 0u};
        if (r < NN) {
          float4 f0 = *(const float4*)(A32 + (size_t)r * HH + ks * 32 + lk);
          float4 f1 = *(const float4*)(A32 + (size_t)r * HH + ks * 32 + lk + 4);
          tmp.x = f2b(f0.x) | (f2b(f0.y) << 16);
          tmp.y = f2b(f0.z) | (f2b(f0.w) << 16);
          tmp.z = f2b(f1.x) | (f2b(f1.y) << 16);
          tmp.w = f2b(f1.z) | (f2b(f1.w) << 16);
        }
        a[t] = __builtin_bit_cast(bf16x8, tmp);
      }
#pragma unroll
      for (int n = 0; n < 8; ++n) {
        bf16x8 b = __builtin_bit_cast(bf16x8, *(const uint4*)&Wt[n * 16 + lrow][ks * 32 + lk]);
        acc[0][n] = __builtin_amdgcn_mfma_f32_16x16x32_bf16(b, a[0], acc[0][n], 0, 0, 0);
        acc[1][n] = __builtin_amdgcn_mfma_f32_16x16x32_bf16(b, a[1], acc[1][n], 0, 0, 0);
      }
    }

    float4 b4[8];
#pragma unroll
    for (int n = 0; n < 8; ++n) b4[n] = *(const float4*)(bias + n * 16 + quad * 4);

#pragma unroll
    for (int t = 0; t < 2; ++t) {
      int row = row0 + t * 16 + lrow;
      if (row < NN) {
        uint16_t* orow = Out + (size_t)row * HH;
#pragma unroll
        for (int n = 0; n < 8; ++n) {
          float v0 = fmaxf(acc[t][n][0] + b4[n].x, 0.f);
          float v1 = fmaxf(acc[t][n][1] + b4[n].y, 0.f);
          float v2 = fmaxf(acc[t][n][2] + b4[n].z, 0.f);
          float v3 = fmaxf(acc[t][n][3] + b4[n].w, 0.f);
          uint2 o;
          o.x = f2b(v0) | (f2b(v1) << 16);
          o.y = f2b(v2) | (f2b(v3) << 16);
          *(uint2*)(orow + n * 16 + quad * 4) = o;
        }
      }
    }
  } else if (blockIdx.x < GB + NBLK) {
    // ---------------- cntB: dst-bucket histogram (LDS) ----------------
    int* h = (int*)smraw;
    int b = blockIdx.x - GB;
    if (tid < NB) h[tid] = 0;
    __syncthreads();
    int base = b * CHUNK, end = min(base + CHUNK, NE);
    for (int i = base + tid; i < end; i += 256) atomicAdd(&h[dst[i] >> BSH], 1);
    __syncthreads();
    if (tid < NB) blkcntB[tid * NBLK + b] = h[tid];   // transposed
  } else if (blockIdx.x < GB + NBLK + 128) {
    // conv layers 1,2 fp32 [k][n] -> bf16 [n][k]; same f2b rounding as stage_w
    int idx = (blockIdx.x - GB - NBLK) * 256 + tid;   // 0..32767
    int l = idx >> 14;
    int n = (idx >> 7) & 127;
    int k = idx & 127;
    wbf[idx] = (uint16_t)f2b(conv_w[(l + 1) * 16384 + k * 128 + n]);
  } else {
    int i = ((blockIdx.x - GB - NBLK - 128) * 256 + tid) * 4;   // 32 blocks x 1024 floats
    if (i < NG * HH) *(float4*)&pooled[i] = make_float4(0.f, 0.f, 0.f, 0.f);
  }
}

// merged column-scan + global-scan over TRANSPOSED blkcnt: 1 block, 8-wide blocked loads.
__global__ void k_scan(const int* __restrict__ blkcnt, int* __restrict__ poff,
                       int* __restrict__ gbase, int* __restrict__ off, int set_off) {
  __shared__ int s[256];
  int t = threadIdx.x;
  int tot = 0;
  if (t < NB) {
    const int* col = blkcnt + (size_t)t * NBLK;
    int* pcol = poff + (size_t)t * NBLK;
    int r0 = 0;
    for (; r0 + 8 <= NBLK; r0 += 8) {
      int v[8];
#pragma unroll
      for (int j = 0; j < 8; ++j) v[j] = col[r0 + j];
#pragma unroll
      for (int j = 0; j < 8; ++j) { pcol[r0 + j] = tot; tot += v[j]; }
    }
    for (; r0 < NBLK; ++r0) { pcol[r0] = tot; tot += col[r0]; }
  }
  s[t] = (t < NB) ? tot : 0;
  __syncthreads();
  for (int d = 1; d < 256; d <<= 1) {
    int v = (t >= d) ? s[t - d] : 0;
    __syncthreads();
    s[t] += v;
    __syncthreads();
  }
  if (t < NB) gbase[t] = s[t] - tot;
  if (t == 0) { gbase[NB] = NE; if (set_off) off[NN] = NE; }
}

// ================= placeB: dst-bucket sort, packed, direct from edge_index =================
__global__ __launch_bounds__(256) void k_placeB(const int* __restrict__ src,
                                                const int* __restrict__ dst,
                                                const int* __restrict__ poff,
                                                const int* __restrict__ gbase,
                                                uint32_t* __restrict__ outb) {
  __shared__ int cur[NB];
  int t = threadIdx.x;
  if (t < NB) cur[t] = poff[(size_t)t * NBLK + blockIdx.x] + gbase[t];
  __syncthreads();
  int base = blockIdx.x * CHUNK, end = min(base + CHUNK, NE);
  for (int i = base + t; i < end; i += 256) {
    int s = src[i], d = dst[i];
    int p = atomicAdd(&cur[d >> BSH], 1);
    outb[p] = (unsigned)s | (((unsigned)d & (unsigned)BMSK) << 17);
  }
}

// ================= bucket_sort: per-dst-bucket counting sort -> off/inv/csrs + dhist2 ====
// (gstart removed: dead since the aggpool rewrite in r6.)
__global__ __launch_bounds__(256) void k_bucket_sort(
    const uint32_t* __restrict__ pairbuf, const int* __restrict__ gbase,
    int* __restrict__ off, float* __restrict__ inv, int* __restrict__ csrs,
    int* __restrict__ dhist2)
{
  __shared__ int cnt[512];
  __shared__ int loff[512];
  __shared__ int psum[256];
  int b = blockIdx.x;
  int tid = threadIdx.x;
  cnt[tid] = 0; cnt[tid + 256] = 0;
  __syncthreads();
  int s0 = gbase[b], s1 = gbase[b + 1];
  for (int i = s0 + tid; i < s1; i += 256)
    atomicAdd(&cnt[pairbuf[i] >> 17], 1);
  __syncthreads();
  int a0 = cnt[2 * tid], a1 = cnt[2 * tid + 1];
  int s = a0 + a1;
  psum[tid] = s;
  __syncthreads();
  for (int d = 1; d < 256; d <<= 1) {
    int v = (tid >= d) ? psum[tid - d] : 0;
    __syncthreads();
    psum[tid] += v;
    __syncthreads();
  }
  int excl = psum[tid] - s;
  loff[2 * tid] = excl;
  loff[2 * tid + 1] = excl + a0;
  __syncthreads();
  int* h64 = psum;               // psum dead after excl computed
  if (tid < 64) h64[tid] = 0;
  __syncthreads();
#pragma unroll
  for (int k = 0; k < 2; ++k) {
    int i = tid + k * 256;
    int node = b * 512 + i;
    if (node < NN) {
      off[node] = s0 + loff[i];
      inv[node] = rsqrtf((float)cnt[i] + 1.0f);
      int d = cnt[i]; if (d > 63) d = 63;
      atomicAdd(&h64[d], 1);
    }
  }
  __syncthreads();
  if (tid < 64) dhist2[b * 64 + tid] = h64[tid];
  cnt[tid] = loff[tid]; cnt[tid + 256] = loff[tid + 256];   // counters -> cursors
  __syncthreads();
  for (int i = s0 + tid; i < s1; i += 256) {
    uint32_t v = pairbuf[i];
    int p = atomicAdd(&cnt[v >> 17], 1);
    csrs[s0 + p] = (int)(v & 0x1FFFFu);
  }
}

// ================= dscan: LPT cursor bases (descending-degree scan) =================
__global__ void k_dscan(const int* __restrict__ dhist2, int* __restrict__ dcur) {
  int t = threadIdx.x;             // 64 threads
  int sum = 0;
  for (int r = 0; r < NB; ++r) sum += dhist2[r * 64 + (63 - t)];
  int v = sum;
  for (int d = 1; d < 64; d <<= 1) { int u = __shfl_up(v, d); if (t >= d) v += u; }
  dcur[63 - t] = v - sum;
}

// ================= fused dual GEMM (enc2+conv0, prescale) || dplace =================
__global__ __launch_bounds__(256) void k_dualplace(
    const uint16_t* __restrict__ A16,
    const float* __restrict__ Wa, const float* __restrict__ ba,
    const float* __restrict__ Wb, const float* __restrict__ bb,
    const float* __restrict__ scale, uint16_t* __restrict__ Out,
    const int* __restrict__ off, int* __restrict__ dcur, int* __restrict__ order)
{
  __shared__ uint16_t Wt[128][136];
  __shared__ uint16_t tile[128][136];
  const int tid = threadIdx.x;

  if (blockIdx.x < GB) {
    // ---------------- dual GEMM ----------------
    stage_w(Wt, Wa, tid);
    __syncthreads();

    const int lane = tid & 63;
    const int wave = tid >> 6;
    const int lrow = lane & 15;
    const int quad = lane >> 4;
    const int lk = quad * 8;
    const int row0 = blockIdx.x * 128 + wave * 32;
    const int trow0 = wave * 32;

    floatx4 acc[2][8];
#pragma unroll
    for (int t = 0; t < 2; ++t)
#pragma unroll
      for (int n = 0; n < 8; ++n)
        acc[t][n] = (floatx4){0.f, 0.f, 0.f, 0.f};

    // phase 1: global A -> C1 (swapped layout)
#pragma unroll
    for (int ks = 0; ks < 4; ++ks) {
      bf16x8 a[2];
#pragma unroll
      for (int t = 0; t < 2; ++t) {
        int r = row0 + t * 16 + lrow;
        uint4 tmp = {0u, 0u, 0u, 0u};
        if (r < NN) tmp = *(const uint4*)(A16 + (size_t)r * HH + ks * 32 + lk);
        a[t] = __builtin_bit_cast(bf16x8, tmp);
      }
#pragma unroll
      for (int n = 0; n < 8; ++n) {
        bf16x8 b = __builtin_bit_cast(bf16x8, *(const uint4*)&Wt[n * 16 + lrow][ks * 32 + lk]);
        acc[0][n] = __builtin_amdgcn_mfma_f32_16x16x32_bf16(b, a[0], acc[0][n], 0, 0, 0);
        acc[1][n] = __builtin_amdgcn_mfma_f32_16x16x32_bf16(b, a[1], acc[1][n], 0, 0, 0);
      }
    }

    // epilogue 1 -> LDS tile (bias, no relu)
    {
      float4 b4[8];
#pragma unroll
      for (int n = 0; n < 8; ++n) b4[n] = *(const float4*)(ba + n * 16 + quad * 4);
#pragma unroll
      for (int t = 0; t < 2; ++t) {
        int trow = trow0 + t * 16 + lrow;
#pragma unroll
        for (int n = 0; n < 8; ++n) {
          uint2 o;
          o.x = f2b(acc[t][n][0] + b4[n].x) | (f2b(acc[t][n][1] + b4[n].y) << 16);
          o.y = f2b(acc[t][n][2] + b4[n].z) | (f2b(acc[t][n][3] + b4[n].w) << 16);
          *(uint2*)&tile[trow][n * 16 + quad * 4] = o;
        }
      }
    }
    __syncthreads();
    stage_w(Wt, Wb, tid);
#pragma unroll
    for (int t = 0; t < 2; ++t)
#pragma unroll
      for (int n = 0; n < 8; ++n)
        acc[t][n] = (floatx4){0.f, 0.f, 0.f, 0.f};
    __syncthreads();

    // phase 2: LDS tile A -> C2
#pragma unroll
    for (int ks = 0; ks < 4; ++ks) {
      bf16x8 a[2];
#pragma unroll
      for (int t = 0; t < 2; ++t)
        a[t] = __builtin_bit_cast(bf16x8,
                 *(const uint4*)&tile[trow0 + t * 16 + lrow][ks * 32 + lk]);
#pragma unroll
      for (int n = 0; n < 8; ++n) {
        bf16x8 b = __builtin_bit_cast(bf16x8, *(const uint4*)&Wt[n * 16 + lrow][ks * 32 + lk]);
        acc[0][n] = __builtin_amdgcn_mfma_f32_16x16x32_bf16(b, a[0], acc[0][n], 0, 0, 0);
        acc[1][n] = __builtin_amdgcn_mfma_f32_16x16x32_bf16(b, a[1], acc[1][n], 0, 0, 0);
      }
    }

    // epilogue 2 -> global (bias, scale, no relu)
    {
      float4 b4[8];
#pragma unroll
      for (int n = 0; n < 8; ++n) b4[n] = *(const float4*)(bb + n * 16 + quad * 4);
#pragma unroll
      for (int t = 0; t < 2; ++t) {
        int row = row0 + t * 16 + lrow;
        if (row < NN) {
          float sc = scale[row];
          uint16_t* orow = Out + (size_t)row * HH;
#pragma unroll
          for (int n = 0; n < 8; ++n) {
            float v0 = (acc[t][n][0] + b4[n].x) * sc;
            float v1 = (acc[t][n][1] + b4[n].y) * sc;
            float v2 = (acc[t][n][2] + b4[n].z) * sc;
            float v3 = (acc[t][n][3] + b4[n].w) * sc;
            uint2 o;
            o.x = f2b(v0) | (f2b(v1) << 16);
            o.y = f2b(v2) | (f2b(v3) << 16);
            *(uint2*)(orow + n * 16 + quad * 4) = o;
          }
        }
      }
    }
  } else {
    // ---------------- dplace (degree-LPT order) ----------------
    int* h = (int*)Wt;
    int* base = h + 64;
    if (tid < 64) h[tid] = 0;
    __syncthreads();
    int i = (blockIdx.x - GB) * 256 + tid;
    int d = 0, ld = 0;
    if (i < NN) { d = off[i + 1] - off[i]; if (d > 63) d = 63; ld = atomicAdd(&h[d], 1); }
    __syncthreads();
    if (tid < 64) base[tid] = h[tid] ? atomicAdd(&dcur[tid], h[tid]) : 0;
    __syncthreads();
    if (i < NN) order[base[d] + ld] = i;
  }
}

// ================= fused agg + conv GEMM (v2: W from L1-resident global) =================
__global__ __launch_bounds__(512) void k_aggemm(
    const uint16_t* __restrict__ hw2, const int* __restrict__ off,
    const int* __restrict__ csrs, const float* __restrict__ inv,
    const int* __restrict__ order,
    const uint16_t* __restrict__ Wbf, const float* __restrict__ bias,
    uint16_t* __restrict__ Out)
{
  __shared__ uint4 S4[32][16];     // [row][chunk], chunk swizzled by row&15
  __shared__ int nid[32];
  const int tid = threadIdx.x;

  // ---- gather phase ----
  const int group = tid >> 4;
  const int node = order[blockIdx.x * 32 + group];
  const int c = (tid & 15) * 8;
  if ((tid & 15) == 0) nid[group] = node;
  const uint16_t* rowp = hw2 + c;

  uint4 sv = *(const uint4*)(rowp + (size_t)node * HH);
  float a[8] = {0.f, 0.f, 0.f, 0.f, 0.f, 0.f, 0.f, 0.f};
  addrow(a, sv);

  int e0 = off[node], e1 = off[node + 1];
  int e = e0;
  for (; e + 4 <= e1; e += 4) {
    int s0 = csrs[e + 0], s1 = csrs[e + 1], s2 = csrs[e + 2], s3 = csrs[e + 3];
    uint4 v0 = *(const uint4*)(rowp + (size_t)s0 * HH);
    uint4 v1 = *(const uint4*)(rowp + (size_t)s1 * HH);
    uint4 v2 = *(const uint4*)(rowp + (size_t)s2 * HH);
    uint4 v3 = *(const uint4*)(rowp + (size_t)s3 * HH);
    addrow(a, v0); addrow(a, v1); addrow(a, v2); addrow(a, v3);
  }
  for (; e < e1; ++e) {
    int s = csrs[e];
    uint4 v = *(const uint4*)(rowp + (size_t)s * HH);
    addrow(a, v);
  }
  float invd = inv[node];
#pragma unroll
  for (int j = 0; j < 8; ++j) a[j] = fmaxf(a[j] * invd, 0.f);
  {
    uint4 o;
    o.x = f2b(a[0]) | (f2b(a[1]) << 16);
    o.y = f2b(a[2]) | (f2b(a[3]) << 16);
    o.z = f2b(a[4]) | (f2b(a[5]) << 16);
    o.w = f2b(a[6]) | (f2b(a[7]) << 16);
    S4[group][(tid & 15) ^ (group & 15)] = o;   // same bf16 rounding as before
  }
  __syncthreads();

  // ---- GEMM phase: wave w computes out-cols [w*16, w*16+16) for all 32 rows ----
  const int lane = tid & 63;
  const int wave = tid >> 6;
  const int lrow = lane & 15;
  const int quad = lane >> 4;
  const int lk = quad * 8;
  const uint16_t* wrow = Wbf + (size_t)(wave * 16 + lrow) * HH;

  floatx4 acc0 = (floatx4){0.f, 0.f, 0.f, 0.f};
  floatx4 acc1 = (floatx4){0.f, 0.f, 0.f, 0.f};
#pragma unroll
  for (int ks = 0; ks < 4; ++ks) {
    int ch = (ks * 4 + quad) ^ lrow;     // swizzled chunk
    bf16x8 a0 = __builtin_bit_cast(bf16x8, S4[lrow][ch]);
    bf16x8 a1 = __builtin_bit_cast(bf16x8, S4[16 + lrow][ch]);
    bf16x8 b  = __builtin_bit_cast(bf16x8, *(const uint4*)(wrow + ks * 32 + lk));
    acc0 = __builtin_amdgcn_mfma_f32_16x16x32_bf16(b, a0, acc0, 0, 0, 0);
    acc1 = __builtin_amdgcn_mfma_f32_16x16x32_bf16(b, a1, acc1, 0, 0, 0);
  }

  float4 b4 = *(const float4*)(bias + wave * 16 + quad * 4);
#pragma unroll
  for (int t = 0; t < 2; ++t) {
    floatx4 ac = t ? acc1 : acc0;
    int row = nid[t * 16 + lrow];
    float sc = inv[row];
    float v0 = (ac[0] + b4.x) * sc;
    float v1 = (ac[1] + b4.y) * sc;
    float v2 = (ac[2] + b4.z) * sc;
    float v3 = (ac[3] + b4.w) * sc;
    uint2 o;
    o.x = f2b(v0) | (f2b(v1) << 16);
    o.y = f2b(v2) | (f2b(v3) << 16);
    *(uint2*)(Out + (size_t)row * HH + wave * 16 + quad * 4) = o;
  }
}

// ================= fused final agg + global_add_pool =================
__global__ __launch_bounds__(256) void k_aggpool(
    const uint16_t* __restrict__ hw2, const int* __restrict__ off,
    const int* __restrict__ csrs, const float* __restrict__ inv,
    const int* __restrict__ batch,
    float* __restrict__ pooled)
{
  __shared__ float red[16][132];
  __shared__ int gid[16];
  const int tid = threadIdx.x;
  const int slot = tid >> 4;
  const int node = blockIdx.x * 16 + slot;    // NN = 6250*16 exactly
  const int c = (tid & 15) * 8;
  if ((tid & 15) == 0) gid[slot] = batch[node];
  const uint16_t* rowp = hw2 + c;

  uint4 sv = *(const uint4*)(rowp + (size_t)node * HH);
  float a[8] = {0.f, 0.f, 0.f, 0.f, 0.f, 0.f, 0.f, 0.f};
  addrow(a, sv);

  int e0 = off[node], e1 = off[node + 1];
  int e = e0;
  for (; e + 4 <= e1; e += 4) {
    int s0 = csrs[e + 0], s1 = csrs[e + 1], s2 = csrs[e + 2], s3 = csrs[e + 3];
    uint4 v0 = *(const uint4*)(rowp + (size_t)s0 * HH);
    uint4 v1 = *(const uint4*)(rowp + (size_t)s1 * HH);
    uint4 v2 = *(const uint4*)(rowp + (size_t)s2 * HH);
    uint4 v3 = *(const uint4*)(rowp + (size_t)s3 * HH);
    addrow(a, v0); addrow(a, v1); addrow(a, v2); addrow(a, v3);
  }
  for (; e < e1; ++e) {
    int s = csrs[e];
    uint4 v = *(const uint4*)(rowp + (size_t)s * HH);
    addrow(a, v);
  }
  float invd = inv[node];
#pragma unroll
  for (int j = 0; j < 8; ++j) a[j] *= invd;
  *(float4*)&red[slot][c]     = make_float4(a[0], a[1], a[2], a[3]);
  *(float4*)&red[slot][c + 4] = make_float4(a[4], a[5], a[6], a[7]);
  __syncthreads();

  if (tid < 128) {
    int g = gid[0];
    float run = red[0][tid];
    for (int r = 1; r < 16; ++r) {
      int gg = gid[r];
      if (gg != g) {
        unsafeAtomicAdd(&pooled[(size_t)g * HH + tid], run);
        run = 0.f; g = gg;
      }
      run += red[r][tid];
    }
    unsafeAtomicAdd(&pooled[(size_t)g * HH + tid], run);
  }
}

// ================= decoder: one block per graph, reads pooled f32 =================
__global__ __launch_bounds__(256) void k_dec(
    const float* __restrict__ pooled,
    const float* __restrict__ w1, const float* __restrict__ b1,
    const float* __restrict__ w2, const float* __restrict__ b2,
    float* __restrict__ out)
{
  __shared__ float p[128], tmpv[128];
  int g = blockIdx.x;
  int tid = threadIdx.x;
  if (tid < 128) p[tid] = pooled[(size_t)g * HH + tid];
  __syncthreads();
  if (tid < 128) {
    float acc1 = b1[tid];
    for (int k = 0; k < 128; ++k) acc1 += p[k] * w1[k * 128 + tid];
    tmpv[tid] = fmaxf(acc1, 0.f);
  }
  __syncthreads();
  if (tid < 10) {
    float o = b2[tid];
    for (int k = 0; k < 128; ++k) o += tmpv[k] * w2[k * 10 + tid];
    out[g * 10 + tid] = o;
  }
}

extern "C" void kernel_launch(void* const* d_in, const int* in_sizes, int n_in,
                              void* d_out, int out_size, void* d_ws, size_t ws_size,
                              hipStream_t stream) {
  const float* x       = (const float*)d_in[0];
  const int*   eidx    = (const int*)d_in[1];
  const int*   src     = eidx;            // edge_index[0]
  const int*   dst     = eidx + NE;       // edge_index[1]
  const int*   batch   = (const int*)d_in[3];
  const float* enc_w1  = (const float*)d_in[4];
  const float* enc_b1  = (const float*)d_in[5];
  const float* enc_w2  = (const float*)d_in[6];
  const float* enc_b2  = (const float*)d_in[7];
  const float* conv_w  = (const float*)d_in[8];
  const float* conv_b  = (const float*)d_in[9];
  const float* dec_w1  = (const float*)d_in[10];
  const float* dec_b1  = (const float*)d_in[11];
  const float* dec_w2  = (const float*)d_in[12];
  const float* dec_b2  = (const float*)d_in[13];
  float* out = (float*)d_out;

  char* ws = (char*)d_ws;
  size_t o = 0;
  auto alloc = [&](size_t bytes) -> char* {
    char* p = ws + o;
    o += (bytes + 255) & ~(size_t)255;
    return p;
  };
  int*      off     = (int*)alloc((size_t)(NN + 1) * 4);
  int*      csrs    = (int*)alloc((size_t)NE * 4);
  float*    inv     = (float*)alloc((size_t)NN * 4);
  int*      blkcntB = (int*)alloc((size_t)NBLK * NB * 4);   // TRANSPOSED [t*NBLK+r]
  int*      poffB   = (int*)alloc((size_t)NBLK * NB * 4);   // TRANSPOSED
  int*      gbaseB  = (int*)alloc((size_t)(NB + 1) * 4);
  int*      dhist2  = (int*)alloc((size_t)NB * 64 * 4);
  int*      dcur    = (int*)alloc(64 * 4);
  int*      order   = (int*)alloc((size_t)NN * 4);
  float*    pooled  = (float*)alloc((size_t)NG * HH * 4);
  uint16_t* wbf     = (uint16_t*)alloc((size_t)2 * 16384 * 2);   // conv1,2 bf16 [n][k]
  uint32_t* pairB   = (uint32_t*)alloc((size_t)NE * 4);
  uint16_t* buf0    = (uint16_t*)alloc((size_t)NN * HH * 2);
  uint16_t* buf1    = (uint16_t*)alloc((size_t)NN * HH * 2);

  // L1: enc1 GEMM || cntB (dst histogram) || wprep || pooled zero
  k_front<<<dim3(GB + NBLK + 128 + 32), dim3(256), 0, stream>>>(
      dst, blkcntB, conv_w, wbf, pooled, x, enc_w1, enc_b1, buf1);
  // L2: scan B (+ off[NN]=NE)
  k_scan<<<dim3(1), dim3(256), 0, stream>>>(blkcntB, poffB, gbaseB, off, 1);
  // L3: placeB (dst-bucket sort, packed, direct from edge_index)
  k_placeB<<<dim3(NBLK), dim3(256), 0, stream>>>(src, dst, poffB, gbaseB, pairB);
  // L4: bucket_sort -> off/inv/csrs + dhist2
  k_bucket_sort<<<dim3(NB), dim3(256), 0, stream>>>(pairB, gbaseB, off, inv, csrs, dhist2);
  // L5: dscan (LPT cursor bases)
  k_dscan<<<dim3(1), dim3(64), 0, stream>>>(dhist2, dcur);
  // L6: dual GEMM (enc2 + conv0 + prescale) || dplace (LPT order)
  k_dualplace<<<dim3(GB + NBK), dim3(256), 0, stream>>>(buf1, enc_w2, enc_b2,
                                                        conv_w + 0 * 16384, conv_b + 0,
                                                        inv, buf0, off, dcur, order);

  // GCN layers: fused [agg + conv GEMM + prescale] x2, then fused [agg + pool]
  const int FB = NN / 32;          // 3125 (32 nodes/block, 512 threads)
  const int AB = NN / 16;          // 6250
  k_aggemm<<<dim3(FB), dim3(512), 0, stream>>>(buf0, off, csrs, inv, order,
                                               wbf, conv_b + 128, buf1);
  k_aggemm<<<dim3(FB), dim3(512), 0, stream>>>(buf1, off, csrs, inv, order,
                                               wbf + 16384, conv_b + 256, buf0);
  k_aggpool<<<dim3(AB), dim3(256), 0, stream>>>(buf0, off, csrs, inv, batch, pooled);

  // decoder
  k_dec<<<dim3(NG), dim3(256), 0, stream>>>(pooled, dec_w1, dec_b1, dec_w2, dec_b2, out);
}